// Round 12
// baseline (147.222 us; speedup 1.0000x reference)
//
#include <hip/hip_runtime.h>
#include <hip/hip_bf16.h>

// B=4, N=4096, C=F=128.  out = softmax(QK^T) V + x.
// R12: revert R11's V-to-VGPR (compiler re-sinks VGPR loads -> serialization;
// attn 59->70). Back to R10's single-buffer K+V DMA loop, scaled to BM=128
// with 4 waves (M=32/wave unchanged): staging per Q-row halves, K/V L2
// traffic halves (512->262 MB), 4 waves share each staged tile, SPLITS=6
// (grid 768, 2 blocks/CU at VGPR~180, 8 waves/CU vs R10's ~6).

#define TOKENS 16384
#define NSEQ   4096
#define DIM    128
#define SPLITS 6

using bf16x8  = __attribute__((ext_vector_type(8))) __bf16;
using f16x8   = __attribute__((ext_vector_type(8))) _Float16;
using floatx4 = __attribute__((ext_vector_type(4))) float;

typedef const __attribute__((address_space(1))) unsigned int g_u32;
typedef __attribute__((address_space(3))) unsigned int l_u32;

__device__ __forceinline__ unsigned short f2bf(float f) {
  unsigned u = __float_as_uint(f);
  u += 0x7FFFu + ((u >> 16) & 1u);   // round-to-nearest-even
  return (unsigned short)(u >> 16);
}
__device__ __forceinline__ float bf2f(unsigned short h) {
  return __uint_as_float(((unsigned)h) << 16);
}
__device__ __forceinline__ unsigned short f2h(float f) {
  union { _Float16 h; unsigned short s; } u;
  u.h = (_Float16)f;
  return u.s;
}

// Fragment layouts in workspace (frag = 64 lanes x 8 shorts = 512 shorts):
//   KF[b][j(64)][nt(4)][kt(4)][lane][8] : K[n=nt*16+l16][k=kt*32+quad*8+e], fp16
//   VF[b][j(64)][nt(8)][kt(2)][lane][8] : V[key=kt*32+quad*8+e][d=nt*16+l16], bf16

// ---------------------------------------------------------------------------
// Kernel 1: QKV projection as MFMA GEMM, bf16 hi/lo 3-pass (fp32-accurate).
// Grid (6,128): x = 64-col slice (matrix-uniform), y = 128-token tile, 4 waves.
// W B-frags gathered per-lane from global fp32 (L2-hot) + hi/lo split in regs.
// Epilogue via LDS transpose -> dest-contiguous b128 stores.
// Outputs: Q fp16 row-major; K fp16 fragment layout; V bf16 fragment layout.
// ---------------------------------------------------------------------------
__global__ __launch_bounds__(256, 2) void qkv_gemm(
    const float* __restrict__ X,
    const float* __restrict__ Wq, const float* __restrict__ Wk,
    const float* __restrict__ Wv,
    const float* __restrict__ bq, const float* __restrict__ bk,
    const float* __restrict__ bv,
    unsigned short* __restrict__ Qh, unsigned short* __restrict__ KF,
    unsigned short* __restrict__ VF)
{
  __shared__ __align__(16) unsigned short sOut[128 * 72]; // out tile [row][col]

  const int tid  = threadIdx.x;
  const int w    = tid >> 6;
  const int lane = tid & 63;
  const int l16  = lane & 15;
  const int quad = lane >> 4;
  const int n0   = blockIdx.x * 64;
  const int m0b  = blockIdx.y * 128;
  const int m0   = m0b + w * 32;
  const int mat  = n0 >> 7;                      // 0=Q, 1=K, 2=V
  const int fbase = n0 & 127;
  const float* Wsrc = (mat == 0) ? Wq : (mat == 1) ? Wk : Wv;

  // A-fragments from X with in-register hi/lo split.
  bf16x8 xh[2][4], xl[2][4];
#pragma unroll
  for (int mt = 0; mt < 2; ++mt) {
    const float* xp = X + (size_t)(m0 + mt * 16 + l16) * 128 + quad * 8;
#pragma unroll
    for (int kt = 0; kt < 4; ++kt) {
      const float4 a = *reinterpret_cast<const float4*>(xp + kt * 32);
      const float4 c = *reinterpret_cast<const float4*>(xp + kt * 32 + 4);
      union { bf16x8 v; unsigned short s[8]; } uh, ul;
      const float xs[8] = {a.x, a.y, a.z, a.w, c.x, c.y, c.z, c.w};
#pragma unroll
      for (int e = 0; e < 8; ++e) {
        const unsigned short hs = f2bf(xs[e]);
        uh.s[e] = hs;
        ul.s[e] = f2bf(xs[e] - bf2f(hs));
      }
      xh[mt][kt] = uh.v;
      xl[mt][kt] = ul.v;
    }
  }

  floatx4 acc[2][4];
#pragma unroll
  for (int mt = 0; mt < 2; ++mt)
#pragma unroll
    for (int nt = 0; nt < 4; ++nt) acc[mt][nt] = (floatx4)(0.0f);

  // C = Xh*Wh + Xl*Wh + Xh*Wl (lo*lo dropped). W gathered per nt:
  // B-frag element (n=nt*16+l16, k=kt*32+quad*8+e) = W[k][fbase+n].
#pragma unroll
  for (int nt = 0; nt < 4; ++nt) {
    bf16x8 bh[4], bl[4];
#pragma unroll
    for (int kt = 0; kt < 4; ++kt) {
      union { bf16x8 v; unsigned short s[8]; } uh, ul;
#pragma unroll
      for (int e = 0; e < 8; ++e) {
        const float wv = Wsrc[(size_t)(kt * 32 + quad * 8 + e) * 128 +
                              fbase + nt * 16 + l16];
        const unsigned short hs = f2bf(wv);
        uh.s[e] = hs;
        ul.s[e] = f2bf(wv - bf2f(hs));
      }
      bh[kt] = uh.v;
      bl[kt] = ul.v;
    }
#pragma unroll
    for (int kt = 0; kt < 4; ++kt)
#pragma unroll
      for (int mt = 0; mt < 2; ++mt) {
        acc[mt][nt] = __builtin_amdgcn_mfma_f32_16x16x32_bf16(xh[mt][kt], bh[kt], acc[mt][nt], 0, 0, 0);
        acc[mt][nt] = __builtin_amdgcn_mfma_f32_16x16x32_bf16(xl[mt][kt], bh[kt], acc[mt][nt], 0, 0, 0);
        acc[mt][nt] = __builtin_amdgcn_mfma_f32_16x16x32_bf16(xh[mt][kt], bl[kt], acc[mt][nt], 0, 0, 0);
      }
  }

  // --- Epilogue: bias + convert -> sOut [128 rows][72 pad shorts] ---
  const float* bias_p = (mat == 0) ? bq : (mat == 1) ? bk : bv;
  float bias[4];
#pragma unroll
  for (int nt = 0; nt < 4; ++nt) bias[nt] = bias_p[fbase + nt * 16 + l16];

#pragma unroll
  for (int mt = 0; mt < 2; ++mt)
#pragma unroll
    for (int nt = 0; nt < 4; ++nt)
#pragma unroll
      for (int r = 0; r < 4; ++r) {
        const float val = acc[mt][nt][r] + bias[nt];
        sOut[(w * 32 + mt * 16 + quad * 4 + r) * 72 + nt * 16 + l16] =
            (mat == 2) ? f2bf(val) : f2h(val);
      }
  __syncthreads();

  // --- Store phase: 1024 x 16-B dest-contiguous chunks, 4/thread ---
  if (mat == 0) {
#pragma unroll
    for (int i = 0; i < 4; ++i) {
      const int c = i * 256 + tid, row = c >> 3, c8 = c & 7;
      *reinterpret_cast<uint4*>(Qh + (size_t)(m0b + row) * DIM + fbase + c8 * 8) =
          *reinterpret_cast<const uint4*>(&sOut[row * 72 + c8 * 8]);
    }
  } else if (mat == 1) {
#pragma unroll
    for (int i = 0; i < 4; ++i) {
      const int c = i * 256 + tid, row = c >> 3, c8 = c & 7;
      const int token = m0b + row;
      const int bK = token >> 12, j = (token & (NSEQ - 1)) >> 6, nl = token & 63;
      const int nt = nl >> 4, lk = nl & 15;
      const int feat = fbase + c8 * 8;
      const int kt = feat >> 5, qd = (feat >> 3) & 3;
      const size_t addr =
          ((((size_t)(bK * 64 + j) * 4 + nt) * 4 + kt) * 64 + qd * 16 + lk) * 8;
      *reinterpret_cast<uint4*>(KF + addr) =
          *reinterpret_cast<const uint4*>(&sOut[row * 72 + c8 * 8]);
    }
  } else {
#pragma unroll
    for (int i = 0; i < 4; ++i) {
      const int c = i * 256 + tid;
      const int d_loc = c & 63, key8 = c >> 6;
      const int d = fbase + d_loc, nt = d >> 4, lv = d & 15;
      const int k7 = key8 & 7, kt = k7 >> 2, qd = k7 & 3;
      const int token0 = m0b + key8 * 8;
      const int bV = token0 >> 12, j = (token0 & (NSEQ - 1)) >> 6;
      unsigned short tmp[8];
#pragma unroll
      for (int e = 0; e < 8; ++e) tmp[e] = sOut[(key8 * 8 + e) * 72 + d_loc];
      const size_t addr =
          ((((size_t)(bV * 64 + j) * 8 + nt) * 2 + kt) * 64 + qd * 16 + lv) * 8;
      *reinterpret_cast<uint4*>(VF + addr) = *reinterpret_cast<const uint4*>(tmp);
    }
  }
}

// ---------------------------------------------------------------------------
// Kernel 2: flash attention, BM=128 x 4 waves (M=32/wave), DMA-staged K+V
// (R10 structure scaled up). Grid 768 = 4b x 6sp x 32qt, 2 blocks/CU.
// Per iter: waves 0-1 DMA the 16 K frags, waves 2-3 the 16 V frags; barrier;
// QK from sK; exp/P via wave-private swizzled LDS; PV from sV; barrier.
// ---------------------------------------------------------------------------
__global__ __launch_bounds__(256, 2) void attn(
    const unsigned short* __restrict__ Qh, const unsigned short* __restrict__ KF,
    const unsigned short* __restrict__ VF,
    unsigned short* __restrict__ Opart, float* __restrict__ Lpart)
{
  __shared__ __align__(16) unsigned short sK[16 * 512];    // 16 K frags, 16 KB
  __shared__ __align__(16) unsigned short sV[16 * 512];    // 16 V frags, 16 KB
  __shared__ __align__(16) unsigned short sP[4 * 32 * 64]; // swizzled, 16 KB

  const int tid  = threadIdx.x;
  const int w    = tid >> 6;
  const int lane = tid & 63;
  const int l16  = lane & 15;
  const int quad = lane >> 4;
  const int b    = blockIdx.x / 192;
  const int rem  = blockIdx.x % 192;
  const int sp   = rem >> 5;            // 0..5
  const int qt   = rem & 31;            // 0..31
  const int q0   = qt * 128;
  const int j0   = (sp < 4) ? sp * 11 : 44 + (sp - 4) * 10;
  const int j1   = j0 + ((sp < 4) ? 11 : 10);

  unsigned short* sPw = &sP[w * 32 * 64];

  // sP XOR swizzle: local row m (0..31), element (m,n) at
  // m*64 + (((n>>3) ^ key(m))<<3) + (n&7), key(m) = (m^(m>>3))&7.
  int wkey[2][4];
#pragma unroll
  for (int mt = 0; mt < 2; ++mt)
#pragma unroll
    for (int r = 0; r < 4; ++r) {
      const int m = mt * 16 + quad * 4 + r;
      wkey[mt][r] = (m ^ (m >> 3)) & 7;
    }
  int rkey[2];
#pragma unroll
  for (int mt = 0; mt < 2; ++mt) {
    const int m = mt * 16 + l16;
    rkey[mt] = (m ^ (m >> 3)) & 7;
  }

  // Q A-frags (fp16): A[m=l16][k=quad*8+e], rows w*32 + mt*16 + l16.
  f16x8 aq[2][4];
#pragma unroll
  for (int mt = 0; mt < 2; ++mt) {
    const unsigned short* qp =
        Qh + (size_t)(b * NSEQ + q0 + w * 32 + mt * 16 + l16) * DIM + quad * 8;
#pragma unroll
    for (int kt = 0; kt < 4; ++kt)
      aq[mt][kt] = *reinterpret_cast<const f16x8*>(qp + kt * 32);
  }

  floatx4 o[2][8];
#pragma unroll
  for (int mt = 0; mt < 2; ++mt)
#pragma unroll
    for (int nt = 0; nt < 8; ++nt) o[mt][nt] = (floatx4)(0.0f);
  float l_part[2][4] = {{0, 0, 0, 0}, {0, 0, 0, 0}};

  for (int j = j0; j < j1; ++j) {
    // --- Stage via async DMA: waves 0-1 -> K frags, waves 2-3 -> V frags ---
    {
      const unsigned short* src = (w < 2) ? KF : VF;
      unsigned short* dst = (w < 2) ? sK : sV;
      const int f0 = (w & 1) * 8;
      const unsigned short* gp = src + (size_t)(b * 64 + j) * 8192 + lane * 8;
#pragma unroll
      for (int f = 0; f < 8; ++f)
        __builtin_amdgcn_global_load_lds(
            (g_u32*)(gp + (f0 + f) * 512), (l_u32*)(dst + (f0 + f) * 512),
            16, 0, 0);
    }
    __syncthreads();   // vmcnt drain + visibility to all 4 waves

    // S = Q K^T (fp16). K frag (nt,kt) at sK[(nt*4+kt)*512 + lane*8].
    floatx4 s[2][4];
#pragma unroll
    for (int mt = 0; mt < 2; ++mt)
#pragma unroll
      for (int nt = 0; nt < 4; ++nt) s[mt][nt] = (floatx4)(0.0f);
#pragma unroll
    for (int nt = 0; nt < 4; ++nt) {
      f16x8 bk[4];
#pragma unroll
      for (int kt = 0; kt < 4; ++kt)
        bk[kt] = *reinterpret_cast<const f16x8*>(
            &sK[(nt * 4 + kt) * 512 + lane * 8]);
#pragma unroll
      for (int kt = 0; kt < 4; ++kt)
#pragma unroll
        for (int mt = 0; mt < 2; ++mt)
          s[mt][nt] = __builtin_amdgcn_mfma_f32_16x16x32_f16(aq[mt][kt], bk[kt], s[mt][nt], 0, 0, 0);
    }

    // No-max softmax (logits bounded ~70 < fp32 exp limit); P bf16 (range).
#pragma unroll
    for (int mt = 0; mt < 2; ++mt)
#pragma unroll
      for (int nt = 0; nt < 4; ++nt)
#pragma unroll
        for (int r = 0; r < 4; ++r) {
          const float p = __expf(s[mt][nt][r]);
          l_part[mt][r] += p;
          sPw[(mt * 16 + quad * 4 + r) * 64 +
              (((nt * 2 + (l16 >> 3)) ^ wkey[mt][r]) << 3) + (l16 & 7)] = f2bf(p);
        }

    // P A-frags (wave-private LDS, no barrier) + V B-frags from LDS.
    bf16x8 ap[2][2];
#pragma unroll
    for (int mt = 0; mt < 2; ++mt)
#pragma unroll
      for (int kt = 0; kt < 2; ++kt)
        ap[mt][kt] = *reinterpret_cast<const bf16x8*>(
            &sPw[(mt * 16 + l16) * 64 + (((kt * 4 + quad) ^ rkey[mt]) << 3)]);

#pragma unroll
    for (int nt = 0; nt < 8; ++nt) {
      bf16x8 bv[2];
#pragma unroll
      for (int kt = 0; kt < 2; ++kt)
        bv[kt] = *reinterpret_cast<const bf16x8*>(
            &sV[(nt * 2 + kt) * 512 + lane * 8]);
#pragma unroll
      for (int kt = 0; kt < 2; ++kt)
#pragma unroll
        for (int mt = 0; mt < 2; ++mt)
          o[mt][nt] = __builtin_amdgcn_mfma_f32_16x16x32_bf16(ap[mt][kt], bv[kt], o[mt][nt], 0, 0, 0);
    }
    __syncthreads();   // protect sK/sV from next iter's DMA overwrite
  }

  // Epilogue: reduce l over 16 cols, store normalized bf16 O-part + l-part.
#pragma unroll
  for (int mt = 0; mt < 2; ++mt)
#pragma unroll
    for (int r = 0; r < 4; ++r) {
      float l = l_part[mt][r];
      l += __shfl_xor(l, 1);
      l += __shfl_xor(l, 2);
      l += __shfl_xor(l, 4);
      l += __shfl_xor(l, 8);
      const float inv = 1.0f / l;
      const int t = q0 + w * 32 + mt * 16 + quad * 4 + r;
      const size_t ob = ((size_t)sp * TOKENS + b * NSEQ + t) * DIM;
#pragma unroll
      for (int nt = 0; nt < 8; ++nt)
        Opart[ob + nt * 16 + l16] = f2bf(o[mt][nt][r] * inv);
      if (l16 == 0) Lpart[sp * TOKENS + b * NSEQ + t] = l;
    }
}

// ---------------------------------------------------------------------------
// Kernel 3: combine sixths + residual. out = sum(l_s O_s)/sum(l_s) + x.
// ---------------------------------------------------------------------------
__global__ __launch_bounds__(256) void combine(
    const unsigned short* __restrict__ Opart, const float* __restrict__ Lpart,
    const float* __restrict__ X, float* __restrict__ Out)
{
  const int idx = blockIdx.x * 256 + threadIdx.x;
  const int T   = idx >> 4;
  const int c8  = (idx & 15) * 8;
  float ls[SPLITS], tot = 0.0f;
#pragma unroll
  for (int s = 0; s < SPLITS; ++s) { ls[s] = Lpart[s * TOKENS + T]; tot += ls[s]; }
  const float winv = 1.0f / tot;

  const size_t pa = (size_t)T * DIM + c8;
  const float4 x0 = *reinterpret_cast<const float4*>(X + pa);
  const float4 x1 = *reinterpret_cast<const float4*>(X + pa + 4);
  float os[8] = {x0.x, x0.y, x0.z, x0.w, x1.x, x1.y, x1.z, x1.w};
#pragma unroll
  for (int s = 0; s < SPLITS; ++s) {
    const float ws = ls[s] * winv;
    const uint4 u = *reinterpret_cast<const uint4*>(
        Opart + (size_t)s * TOKENS * DIM + pa);
    const unsigned uu[4] = {u.x, u.y, u.z, u.w};
#pragma unroll
    for (int e = 0; e < 4; ++e) {
      os[2 * e]     += ws * bf2f(uu[e] & 0xffff);
      os[2 * e + 1] += ws * bf2f(uu[e] >> 16);
    }
  }
  float4 o0 = {os[0], os[1], os[2], os[3]};
  float4 o1 = {os[4], os[5], os[6], os[7]};
  *reinterpret_cast<float4*>(Out + pa)     = o0;
  *reinterpret_cast<float4*>(Out + pa + 4) = o1;
}

// ---------------------------------------------------------------------------
extern "C" void kernel_launch(void* const* d_in, const int* in_sizes, int n_in,
                              void* d_out, int out_size, void* d_ws, size_t ws_size,
                              hipStream_t stream) {
  const float* X  = (const float*)d_in[0];
  const float* Wq = (const float*)d_in[1];
  const float* bq = (const float*)d_in[2];
  const float* Wk = (const float*)d_in[3];
  const float* bk = (const float*)d_in[4];
  const float* Wv = (const float*)d_in[5];
  const float* bv = (const float*)d_in[6];
  float* Out = (float*)d_out;

  const size_t MAT = (size_t)TOKENS * DIM;   // 2 M elements
  unsigned short* Qh    = (unsigned short*)d_ws;          // fp16 row-major, 4MB
  unsigned short* KF    = Qh + MAT;                       // fp16 frag, 4MB
  unsigned short* VF    = KF + MAT;                       // bf16 frag, 4MB
  unsigned short* Opart = VF + MAT;                       // bf16, SPLITS x 4MB
  float*          Lpart = (float*)(Opart + (size_t)SPLITS * MAT);
  // total ws ~ 36.4 MB

  qkv_gemm<<<dim3(6, 128), 256, 0, stream>>>(X, Wq, Wk, Wv, bq, bk, bv,
                                             Qh, KF, VF);
  attn<<<4 * SPLITS * 32, 256, 0, stream>>>(Qh, KF, VF, Opart, Lpart);
  combine<<<(TOKENS * DIM) / (256 * 8), 256, 0, stream>>>(Opart, Lpart, X, Out);
}

// Round 13
// 142.408 us; speedup vs baseline: 1.0338x; 1.0338x over previous
//
#include <hip/hip_runtime.h>
#include <hip/hip_bf16.h>

// B=4, N=4096, C=F=128.  out = softmax(QK^T) V + x.
// R13: attn reverted to EXACT R10 (59.2 us, best measured). The hidden hog
// was qkv (~55-60 us for 1.6 GFLOP): its X A-frag path interleaved VGPR
// global loads with dependent hi/lo converts -> full latency serialization
// (same disease attn had pre-R10). Cure: prep kernel streams X and W into
// fragment-layout bf16 hi/lo; qkv_gemm ingests everything via global_load_lds
// DMA (un-sinkable), one barrier, conflict-free ds_read_b128, 48 MFMA,
// LDS-transpose epilogue. Zero VGPR-destined global loads in qkv.

#define TOKENS 16384
#define NSEQ   4096
#define DIM    128
#define SPLITS 4
#define JSPL   16            // 64 key-tiles / 4 splits

using bf16x8  = __attribute__((ext_vector_type(8))) __bf16;
using f16x8   = __attribute__((ext_vector_type(8))) _Float16;
using floatx4 = __attribute__((ext_vector_type(4))) float;

typedef const __attribute__((address_space(1))) unsigned int g_u32;
typedef __attribute__((address_space(3))) unsigned int l_u32;

__device__ __forceinline__ unsigned short f2bf(float f) {
  unsigned u = __float_as_uint(f);
  u += 0x7FFFu + ((u >> 16) & 1u);   // round-to-nearest-even
  return (unsigned short)(u >> 16);
}
__device__ __forceinline__ float bf2f(unsigned short h) {
  return __uint_as_float(((unsigned)h) << 16);
}
__device__ __forceinline__ unsigned short f2h(float f) {
  union { _Float16 h; unsigned short s; } u;
  u.h = (_Float16)f;
  return u.s;
}

// Fragment layouts in workspace (frag = 64 lanes x 8 shorts = 512 shorts):
//   KF[b][j(64)][nt(4)][kt(4)][lane][8] : K[n=nt*16+l16][k=kt*32+quad*8+e], fp16
//   VF[b][j(64)][nt(8)][kt(2)][lane][8] : V[key=kt*32+quad*8+e][d=nt*16+l16], bf16
//   XFh/XFl[tile(1024)][kt(4)][lane][8] : X[m=tile*16+l16][k=kt*32+quad*8+e], bf16 hi/lo
//   WFh/WFl[slice(6)][nt(4)][kt(4)][lane][8] : W[n=slice*64+nt*16+l16][k], bf16 hi/lo

// ---------------------------------------------------------------------------
// Kernel 0: prep. Blocks 0..255: X -> XFh/XFl (4 row-tiles of 16 each).
// Blocks 256..261: W slice -> WFh/WFl. All reads/writes coalesced via LDS tile.
// ---------------------------------------------------------------------------
__global__ __launch_bounds__(256) void prep(
    const float* __restrict__ X,
    const float* __restrict__ Wq, const float* __restrict__ Wk,
    const float* __restrict__ Wv,
    unsigned short* __restrict__ XFh, unsigned short* __restrict__ XFl,
    unsigned short* __restrict__ WFh, unsigned short* __restrict__ WFl)
{
  __shared__ float sBuf[8704];   // A: [64][132] fp32; B: [128][68] fp32

  const int tid  = threadIdx.x;
  const int w    = tid >> 6;
  const int lane = tid & 63;
  const int l16  = lane & 15;
  const int quad = lane >> 4;

  if (blockIdx.x < 256) {
    // --- X prep: 64 rows (4 tiles of 16) ---
    const int m0 = blockIdx.x * 64;
#pragma unroll
    for (int t = 0; t < 8; ++t) {
      const int idx = t * 256 + tid;
      const int row = idx >> 5, col4 = idx & 31;
      const float4 v = *reinterpret_cast<const float4*>(
          X + (size_t)(m0 + row) * DIM + col4 * 4);
      *reinterpret_cast<float4*>(&sBuf[row * 132 + col4 * 4]) = v;
    }
    __syncthreads();
    // wave w -> tile t0+w (local rows w*16..+15)
    const int tile = m0 / 16 + w;
#pragma unroll
    for (int kt = 0; kt < 4; ++kt) {
      union { uint4 u; unsigned short s[8]; } uh, ul;
#pragma unroll
      for (int e = 0; e < 8; ++e) {
        const float xv = sBuf[(w * 16 + l16) * 132 + kt * 32 + quad * 8 + e];
        const unsigned short hs = f2bf(xv);
        uh.s[e] = hs;
        ul.s[e] = f2bf(xv - bf2f(hs));
      }
      const size_t off = ((size_t)tile * 4 + kt) * 512 + lane * 8;
      *reinterpret_cast<uint4*>(XFh + off) = uh.u;
      *reinterpret_cast<uint4*>(XFl + off) = ul.u;
    }
  } else {
    // --- W prep: one 64-col slice ---
    const int slice = blockIdx.x - 256;           // 0..5
    const int mat = slice >> 1, fbase = (slice & 1) * 64;
    const float* Wsrc = (mat == 0) ? Wq : (mat == 1) ? Wk : Wv;
#pragma unroll
    for (int t = 0; t < 8; ++t) {
      const int idx = t * 256 + tid;
      const int k = idx >> 4, c4 = idx & 15;
      const float4 v = *reinterpret_cast<const float4*>(
          Wsrc + (size_t)k * DIM + fbase + c4 * 4);
      *reinterpret_cast<float4*>(&sBuf[k * 68 + c4 * 4]) = v;
    }
    __syncthreads();
    // wave w -> nt = w
#pragma unroll
    for (int kt = 0; kt < 4; ++kt) {
      union { uint4 u; unsigned short s[8]; } uh, ul;
#pragma unroll
      for (int e = 0; e < 8; ++e) {
        const float wv = sBuf[(kt * 32 + quad * 8 + e) * 68 + w * 16 + l16];
        const unsigned short hs = f2bf(wv);
        uh.s[e] = hs;
        ul.s[e] = f2bf(wv - bf2f(hs));
      }
      const size_t off = ((size_t)(slice * 4 + w) * 4 + kt) * 512 + lane * 8;
      *reinterpret_cast<uint4*>(WFh + off) = uh.u;
      *reinterpret_cast<uint4*>(WFl + off) = ul.u;
    }
  }
}

// ---------------------------------------------------------------------------
// Kernel 1: QKV GEMM, all-DMA ingest. Grid (6, 256): x = 64-col slice,
// y = 64-token tile. 4 waves: wave w = DMA role (sXh/sXl/sWh/sWl) and
// compute rows w*16..+16. bf16 hi/lo 3-pass (fp32-accurate).
// Outputs: Q fp16 row-major; K fp16 fragment layout; V bf16 fragment layout.
// ---------------------------------------------------------------------------
__global__ __launch_bounds__(256, 2) void qkv_gemm(
    const unsigned short* __restrict__ XFh, const unsigned short* __restrict__ XFl,
    const unsigned short* __restrict__ WFh, const unsigned short* __restrict__ WFl,
    const float* __restrict__ bq, const float* __restrict__ bk,
    const float* __restrict__ bv,
    unsigned short* __restrict__ Qh, unsigned short* __restrict__ KF,
    unsigned short* __restrict__ VF)
{
  __shared__ __align__(16) unsigned short sXh[16 * 512];  // 16 KB
  __shared__ __align__(16) unsigned short sXl[16 * 512];
  __shared__ __align__(16) unsigned short sWh[16 * 512];
  __shared__ __align__(16) unsigned short sWl[16 * 512];
  __shared__ __align__(16) unsigned short sOut[64 * 72];  // 9 KB

  const int tid  = threadIdx.x;
  const int w    = tid >> 6;
  const int lane = tid & 63;
  const int l16  = lane & 15;
  const int quad = lane >> 4;
  const int slice = blockIdx.x;                 // 0..5
  const int mat  = slice >> 1;                  // 0=Q, 1=K, 2=V
  const int fbase = (slice & 1) * 64;
  const int m0   = blockIdx.y * 64;
  const int t0   = blockIdx.y * 4;              // first 16-row tile

  // --- DMA ingest: wave w stages 16 chunks of its buffer ---
  {
    const unsigned short* src;
    unsigned short* dst;
    size_t cbase;
    if (w == 0)      { src = XFh; dst = sXh; cbase = (size_t)t0 * 4; }
    else if (w == 1) { src = XFl; dst = sXl; cbase = (size_t)t0 * 4; }
    else if (w == 2) { src = WFh; dst = sWh; cbase = (size_t)slice * 16; }
    else             { src = WFl; dst = sWl; cbase = (size_t)slice * 16; }
    const unsigned short* gp = src + cbase * 512 + lane * 8;
#pragma unroll
    for (int f = 0; f < 16; ++f)
      __builtin_amdgcn_global_load_lds(
          (g_u32*)(gp + f * 512), (l_u32*)(dst + f * 512), 16, 0, 0);
  }
  __syncthreads();

  // X A-frags for this wave's 16 rows (tile t0+w), conflict-free b128.
  bf16x8 xh[4], xl[4];
#pragma unroll
  for (int kt = 0; kt < 4; ++kt) {
    xh[kt] = *reinterpret_cast<const bf16x8*>(&sXh[(w * 4 + kt) * 512 + lane * 8]);
    xl[kt] = *reinterpret_cast<const bf16x8*>(&sXl[(w * 4 + kt) * 512 + lane * 8]);
  }

  floatx4 acc[4];
#pragma unroll
  for (int nt = 0; nt < 4; ++nt) acc[nt] = (floatx4)(0.0f);

  // C = Xh*Wh + Xl*Wh + Xh*Wl (lo*lo dropped).
#pragma unroll
  for (int nt = 0; nt < 4; ++nt) {
    bf16x8 wh[4], wl[4];
#pragma unroll
    for (int kt = 0; kt < 4; ++kt) {
      wh[kt] = *reinterpret_cast<const bf16x8*>(&sWh[(nt * 4 + kt) * 512 + lane * 8]);
      wl[kt] = *reinterpret_cast<const bf16x8*>(&sWl[(nt * 4 + kt) * 512 + lane * 8]);
    }
#pragma unroll
    for (int kt = 0; kt < 4; ++kt) {
      acc[nt] = __builtin_amdgcn_mfma_f32_16x16x32_bf16(xh[kt], wh[kt], acc[nt], 0, 0, 0);
      acc[nt] = __builtin_amdgcn_mfma_f32_16x16x32_bf16(xl[kt], wh[kt], acc[nt], 0, 0, 0);
      acc[nt] = __builtin_amdgcn_mfma_f32_16x16x32_bf16(xh[kt], wl[kt], acc[nt], 0, 0, 0);
    }
  }

  // --- Epilogue: bias + convert -> sOut [64 rows][72 pad shorts] ---
  const float* bias_p = (mat == 0) ? bq : (mat == 1) ? bk : bv;
  float bias[4];
#pragma unroll
  for (int nt = 0; nt < 4; ++nt) bias[nt] = bias_p[fbase + nt * 16 + l16];

#pragma unroll
  for (int nt = 0; nt < 4; ++nt)
#pragma unroll
    for (int r = 0; r < 4; ++r) {
      const float val = acc[nt][r] + bias[nt];
      sOut[(w * 16 + quad * 4 + r) * 72 + nt * 16 + l16] =
          (mat == 2) ? f2bf(val) : f2h(val);
    }
  __syncthreads();

  // --- Store phase: 512 x 16-B dest-contiguous chunks, 2/thread ---
  if (mat == 0) {
#pragma unroll
    for (int i = 0; i < 2; ++i) {
      const int c = i * 256 + tid, row = c >> 3, c8 = c & 7;
      *reinterpret_cast<uint4*>(Qh + (size_t)(m0 + row) * DIM + fbase + c8 * 8) =
          *reinterpret_cast<const uint4*>(&sOut[row * 72 + c8 * 8]);
    }
  } else if (mat == 1) {
#pragma unroll
    for (int i = 0; i < 2; ++i) {
      const int c = i * 256 + tid, row = c >> 3, c8 = c & 7;
      const int token = m0 + row;
      const int bK = token >> 12, j = (token & (NSEQ - 1)) >> 6, nl = token & 63;
      const int nt = nl >> 4, lk = nl & 15;
      const int feat = fbase + c8 * 8;
      const int kt = feat >> 5, qd = (feat >> 3) & 3;
      const size_t addr =
          ((((size_t)(bK * 64 + j) * 4 + nt) * 4 + kt) * 64 + qd * 16 + lk) * 8;
      *reinterpret_cast<uint4*>(KF + addr) =
          *reinterpret_cast<const uint4*>(&sOut[row * 72 + c8 * 8]);
    }
  } else {
#pragma unroll
    for (int i = 0; i < 2; ++i) {
      const int c = i * 256 + tid;
      const int d_loc = c & 63, key8 = c >> 6;            // key8: 0..7
      const int d = fbase + d_loc, nt = d >> 4, lv = d & 15;
      const int kt = key8 >> 2, qd = key8 & 3;
      const int token0 = m0 + key8 * 8;
      const int bV = token0 >> 12, j = (token0 & (NSEQ - 1)) >> 6;
      unsigned short tmp[8];
#pragma unroll
      for (int e = 0; e < 8; ++e) tmp[e] = sOut[(key8 * 8 + e) * 72 + d_loc];
      const size_t addr =
          ((((size_t)(bV * 64 + j) * 8 + nt) * 2 + kt) * 64 + qd * 16 + lv) * 8;
      *reinterpret_cast<uint4*>(VF + addr) = *reinterpret_cast<const uint4*>(tmp);
    }
  }
}

// ---------------------------------------------------------------------------
// Kernel 2: flash attention quarter, async-DMA staged (EXACT R10, 59.2 us).
// 1024 blocks x 128 threads (2 waves, M=32/wave) = 4 blocks/CU.
// ---------------------------------------------------------------------------
__global__ __launch_bounds__(128, 2) void attn(
    const unsigned short* __restrict__ Qh, const unsigned short* __restrict__ KF,
    const unsigned short* __restrict__ VF,
    unsigned short* __restrict__ Opart, float* __restrict__ Lpart)
{
  __shared__ __align__(16) unsigned short sK[16 * 512];    // 16 K frags, 16 KB
  __shared__ __align__(16) unsigned short sV[16 * 512];    // 16 V frags, 16 KB
  __shared__ __align__(16) unsigned short sP[2 * 32 * 64]; // swizzled, 8 KB

  const int tid  = threadIdx.x;
  const int w    = tid >> 6;
  const int lane = tid & 63;
  const int l16  = lane & 15;
  const int quad = lane >> 4;
  const int b    = blockIdx.x >> 8;
  const int sp   = (blockIdx.x >> 6) & 3;
  const int qt   = blockIdx.x & 63;
  const int q0   = qt * 64;
  const int j0   = sp * JSPL, j1 = j0 + JSPL;

  unsigned short* sPw = &sP[w * 32 * 64];

  int wkey[2][4];
#pragma unroll
  for (int mt = 0; mt < 2; ++mt)
#pragma unroll
    for (int r = 0; r < 4; ++r) {
      const int m = mt * 16 + quad * 4 + r;
      wkey[mt][r] = (m ^ (m >> 3)) & 7;
    }
  int rkey[2];
#pragma unroll
  for (int mt = 0; mt < 2; ++mt) {
    const int m = mt * 16 + l16;
    rkey[mt] = (m ^ (m >> 3)) & 7;
  }

  f16x8 aq[2][4];
#pragma unroll
  for (int mt = 0; mt < 2; ++mt) {
    const unsigned short* qp =
        Qh + (size_t)(b * NSEQ + q0 + w * 32 + mt * 16 + l16) * DIM + quad * 8;
#pragma unroll
    for (int kt = 0; kt < 4; ++kt)
      aq[mt][kt] = *reinterpret_cast<const f16x8*>(qp + kt * 32);
  }

  floatx4 o[2][8];
#pragma unroll
  for (int mt = 0; mt < 2; ++mt)
#pragma unroll
    for (int nt = 0; nt < 8; ++nt) o[mt][nt] = (floatx4)(0.0f);
  float l_part[2][4] = {{0, 0, 0, 0}, {0, 0, 0, 0}};

  for (int j = j0; j < j1; ++j) {
    {
      const unsigned short* src = (w == 0) ? KF : VF;
      unsigned short* dst = (w == 0) ? sK : sV;
      const unsigned short* gp = src + (size_t)(b * 64 + j) * 8192 + lane * 8;
#pragma unroll
      for (int f = 0; f < 16; ++f)
        __builtin_amdgcn_global_load_lds(
            (g_u32*)(gp + f * 512), (l_u32*)(dst + f * 512), 16, 0, 0);
    }
    __syncthreads();

    f16x8 bk[4][4];
#pragma unroll
    for (int nt = 0; nt < 4; ++nt)
#pragma unroll
      for (int kt = 0; kt < 4; ++kt)
        bk[nt][kt] = *reinterpret_cast<const f16x8*>(
            &sK[(nt * 4 + kt) * 512 + lane * 8]);

    floatx4 s[2][4];
#pragma unroll
    for (int mt = 0; mt < 2; ++mt)
#pragma unroll
      for (int nt = 0; nt < 4; ++nt) s[mt][nt] = (floatx4)(0.0f);
#pragma unroll
    for (int nt = 0; nt < 4; ++nt)
#pragma unroll
      for (int kt = 0; kt < 4; ++kt)
#pragma unroll
        for (int mt = 0; mt < 2; ++mt)
          s[mt][nt] = __builtin_amdgcn_mfma_f32_16x16x32_f16(aq[mt][kt], bk[nt][kt], s[mt][nt], 0, 0, 0);

#pragma unroll
    for (int mt = 0; mt < 2; ++mt)
#pragma unroll
      for (int nt = 0; nt < 4; ++nt)
#pragma unroll
        for (int r = 0; r < 4; ++r) {
          const float p = __expf(s[mt][nt][r]);
          l_part[mt][r] += p;
          sPw[(mt * 16 + quad * 4 + r) * 64 +
              (((nt * 2 + (l16 >> 3)) ^ wkey[mt][r]) << 3) + (l16 & 7)] = f2bf(p);
        }

    bf16x8 ap[2][2];
#pragma unroll
    for (int mt = 0; mt < 2; ++mt)
#pragma unroll
      for (int kt = 0; kt < 2; ++kt)
        ap[mt][kt] = *reinterpret_cast<const bf16x8*>(
            &sPw[(mt * 16 + l16) * 64 + (((kt * 4 + quad) ^ rkey[mt]) << 3)]);

#pragma unroll
    for (int nt = 0; nt < 8; ++nt) {
      bf16x8 bv[2];
#pragma unroll
      for (int kt = 0; kt < 2; ++kt)
        bv[kt] = *reinterpret_cast<const bf16x8*>(
            &sV[(nt * 2 + kt) * 512 + lane * 8]);
#pragma unroll
      for (int kt = 0; kt < 2; ++kt)
#pragma unroll
        for (int mt = 0; mt < 2; ++mt)
          o[mt][nt] = __builtin_amdgcn_mfma_f32_16x16x32_bf16(ap[mt][kt], bv[kt], o[mt][nt], 0, 0, 0);
    }
    __syncthreads();
  }

#pragma unroll
  for (int mt = 0; mt < 2; ++mt)
#pragma unroll
    for (int r = 0; r < 4; ++r) {
      float l = l_part[mt][r];
      l += __shfl_xor(l, 1);
      l += __shfl_xor(l, 2);
      l += __shfl_xor(l, 4);
      l += __shfl_xor(l, 8);
      const float inv = 1.0f / l;
      const int t = q0 + w * 32 + mt * 16 + quad * 4 + r;
      const size_t ob = ((size_t)sp * TOKENS + b * NSEQ + t) * DIM;
#pragma unroll
      for (int nt = 0; nt < 8; ++nt)
        Opart[ob + nt * 16 + l16] = f2bf(o[mt][nt][r] * inv);
      if (l16 == 0) Lpart[sp * TOKENS + b * NSEQ + t] = l;
    }
}

// ---------------------------------------------------------------------------
// Kernel 3: combine quarters + residual. out = sum(l_s O_s)/sum(l_s) + x.
// ---------------------------------------------------------------------------
__global__ __launch_bounds__(256) void combine(
    const unsigned short* __restrict__ Opart, const float* __restrict__ Lpart,
    const float* __restrict__ X, float* __restrict__ Out)
{
  const int idx = blockIdx.x * 256 + threadIdx.x;
  const int T   = idx >> 4;
  const int c8  = (idx & 15) * 8;
  float ls[SPLITS], tot = 0.0f;
#pragma unroll
  for (int s = 0; s < SPLITS; ++s) { ls[s] = Lpart[s * TOKENS + T]; tot += ls[s]; }
  const float winv = 1.0f / tot;

  const size_t pa = (size_t)T * DIM + c8;
  const float4 x0 = *reinterpret_cast<const float4*>(X + pa);
  const float4 x1 = *reinterpret_cast<const float4*>(X + pa + 4);
  float os[8] = {x0.x, x0.y, x0.z, x0.w, x1.x, x1.y, x1.z, x1.w};
#pragma unroll
  for (int s = 0; s < SPLITS; ++s) {
    const float ws = ls[s] * winv;
    const uint4 u = *reinterpret_cast<const uint4*>(
        Opart + (size_t)s * TOKENS * DIM + pa);
    const unsigned uu[4] = {u.x, u.y, u.z, u.w};
#pragma unroll
    for (int e = 0; e < 4; ++e) {
      os[2 * e]     += ws * bf2f(uu[e] & 0xffff);
      os[2 * e + 1] += ws * bf2f(uu[e] >> 16);
    }
  }
  float4 o0 = {os[0], os[1], os[2], os[3]};
  float4 o1 = {os[4], os[5], os[6], os[7]};
  *reinterpret_cast<float4*>(Out + pa)     = o0;
  *reinterpret_cast<float4*>(Out + pa + 4) = o1;
}

// ---------------------------------------------------------------------------
extern "C" void kernel_launch(void* const* d_in, const int* in_sizes, int n_in,
                              void* d_out, int out_size, void* d_ws, size_t ws_size,
                              hipStream_t stream) {
  const float* X  = (const float*)d_in[0];
  const float* Wq = (const float*)d_in[1];
  const float* bq = (const float*)d_in[2];
  const float* Wk = (const float*)d_in[3];
  const float* bk = (const float*)d_in[4];
  const float* Wv = (const float*)d_in[5];
  const float* bv = (const float*)d_in[6];
  float* Out = (float*)d_out;

  const size_t MAT = (size_t)TOKENS * DIM;   // 2 M elements
  unsigned short* Qh    = (unsigned short*)d_ws;          // fp16 row-major, 4MB
  unsigned short* KF    = Qh + MAT;                       // fp16 frag, 4MB
  unsigned short* VF    = KF + MAT;                       // bf16 frag, 4MB
  unsigned short* XFh   = VF + MAT;                       // bf16 frag, 4MB
  unsigned short* XFl   = XFh + MAT;                      // bf16 frag, 4MB
  unsigned short* WFh   = XFl + MAT;                      // 96 KB
  unsigned short* WFl   = WFh + 6 * 16 * 512;             // 96 KB
  unsigned short* Opart = WFl + 6 * 16 * 512;             // bf16, SPLITS x 4MB
  float*          Lpart = (float*)(Opart + (size_t)SPLITS * MAT);
  // total ws ~ 36.5 MB

  prep<<<262, 256, 0, stream>>>(X, Wq, Wk, Wv, XFh, XFl, WFh, WFl);
  qkv_gemm<<<dim3(6, 256), 256, 0, stream>>>(XFh, XFl, WFh, WFl, bq, bk, bv,
                                             Qh, KF, VF);
  attn<<<4 * SPLITS * 64, 128, 0, stream>>>(Qh, KF, VF, Opart, Lpart);
  combine<<<(TOKENS * DIM) / (256 * 8), 256, 0, stream>>>(Opart, Lpart, X, Out);
}

// Round 14
// 140.083 us; speedup vs baseline: 1.0510x; 1.0166x over previous
//
#include <hip/hip_runtime.h>
#include <hip/hip_bf16.h>

// B=4, N=4096, C=F=128.  out = softmax(QK^T) V + x.
// R14: single change vs R13 — XCD-affine block swizzle in attn.
// Diagnosis: attn is bound by K/V reads missing the per-XCD 4MB L2 (KF+VF =
// 8MB working set, no XCD affinity) and streaming from L3 at ~8.7 TB/s
// effective (64 block-iters/CU x 2212 cyc, zero cross-block overlap credit =
// shared-resource bound). Remap blockIdx.x = qt*16 + (b*4+sp): with the
// round-robin %8 XCD heuristic each XCD serves 2 (b,sp) pairs -> 4MB K/V
// slice, L2-resident -> reads at L2 BW/latency instead of L3.

#define TOKENS 16384
#define NSEQ   4096
#define DIM    128
#define SPLITS 4
#define JSPL   16            // 64 key-tiles / 4 splits

using bf16x8  = __attribute__((ext_vector_type(8))) __bf16;
using f16x8   = __attribute__((ext_vector_type(8))) _Float16;
using floatx4 = __attribute__((ext_vector_type(4))) float;

typedef const __attribute__((address_space(1))) unsigned int g_u32;
typedef __attribute__((address_space(3))) unsigned int l_u32;

__device__ __forceinline__ unsigned short f2bf(float f) {
  unsigned u = __float_as_uint(f);
  u += 0x7FFFu + ((u >> 16) & 1u);   // round-to-nearest-even
  return (unsigned short)(u >> 16);
}
__device__ __forceinline__ float bf2f(unsigned short h) {
  return __uint_as_float(((unsigned)h) << 16);
}
__device__ __forceinline__ unsigned short f2h(float f) {
  union { _Float16 h; unsigned short s; } u;
  u.h = (_Float16)f;
  return u.s;
}

// Fragment layouts in workspace (frag = 64 lanes x 8 shorts = 512 shorts):
//   KF[b][j(64)][nt(4)][kt(4)][lane][8] : K[n=nt*16+l16][k=kt*32+quad*8+e], fp16
//   VF[b][j(64)][nt(8)][kt(2)][lane][8] : V[key=kt*32+quad*8+e][d=nt*16+l16], bf16
//   XFh/XFl[tile(1024)][kt(4)][lane][8] : X[m=tile*16+l16][k=kt*32+quad*8+e], bf16 hi/lo
//   WFh/WFl[slice(6)][nt(4)][kt(4)][lane][8] : W[n=slice*64+nt*16+l16][k], bf16 hi/lo

// ---------------------------------------------------------------------------
// Kernel 0: prep. Blocks 0..255: X -> XFh/XFl (4 row-tiles of 16 each).
// Blocks 256..261: W slice -> WFh/WFl. All reads/writes coalesced via LDS tile.
// ---------------------------------------------------------------------------
__global__ __launch_bounds__(256) void prep(
    const float* __restrict__ X,
    const float* __restrict__ Wq, const float* __restrict__ Wk,
    const float* __restrict__ Wv,
    unsigned short* __restrict__ XFh, unsigned short* __restrict__ XFl,
    unsigned short* __restrict__ WFh, unsigned short* __restrict__ WFl)
{
  __shared__ float sBuf[8704];   // A: [64][132] fp32; B: [128][68] fp32

  const int tid  = threadIdx.x;
  const int w    = tid >> 6;
  const int lane = tid & 63;
  const int l16  = lane & 15;
  const int quad = lane >> 4;

  if (blockIdx.x < 256) {
    // --- X prep: 64 rows (4 tiles of 16) ---
    const int m0 = blockIdx.x * 64;
#pragma unroll
    for (int t = 0; t < 8; ++t) {
      const int idx = t * 256 + tid;
      const int row = idx >> 5, col4 = idx & 31;
      const float4 v = *reinterpret_cast<const float4*>(
          X + (size_t)(m0 + row) * DIM + col4 * 4);
      *reinterpret_cast<float4*>(&sBuf[row * 132 + col4 * 4]) = v;
    }
    __syncthreads();
    // wave w -> tile t0+w (local rows w*16..+15)
    const int tile = m0 / 16 + w;
#pragma unroll
    for (int kt = 0; kt < 4; ++kt) {
      union { uint4 u; unsigned short s[8]; } uh, ul;
#pragma unroll
      for (int e = 0; e < 8; ++e) {
        const float xv = sBuf[(w * 16 + l16) * 132 + kt * 32 + quad * 8 + e];
        const unsigned short hs = f2bf(xv);
        uh.s[e] = hs;
        ul.s[e] = f2bf(xv - bf2f(hs));
      }
      const size_t off = ((size_t)tile * 4 + kt) * 512 + lane * 8;
      *reinterpret_cast<uint4*>(XFh + off) = uh.u;
      *reinterpret_cast<uint4*>(XFl + off) = ul.u;
    }
  } else {
    // --- W prep: one 64-col slice ---
    const int slice = blockIdx.x - 256;           // 0..5
    const int mat = slice >> 1, fbase = (slice & 1) * 64;
    const float* Wsrc = (mat == 0) ? Wq : (mat == 1) ? Wk : Wv;
#pragma unroll
    for (int t = 0; t < 8; ++t) {
      const int idx = t * 256 + tid;
      const int k = idx >> 4, c4 = idx & 15;
      const float4 v = *reinterpret_cast<const float4*>(
          Wsrc + (size_t)k * DIM + fbase + c4 * 4);
      *reinterpret_cast<float4*>(&sBuf[k * 68 + c4 * 4]) = v;
    }
    __syncthreads();
    // wave w -> nt = w
#pragma unroll
    for (int kt = 0; kt < 4; ++kt) {
      union { uint4 u; unsigned short s[8]; } uh, ul;
#pragma unroll
      for (int e = 0; e < 8; ++e) {
        const float wv = sBuf[(kt * 32 + quad * 8 + e) * 68 + w * 16 + l16];
        const unsigned short hs = f2bf(wv);
        uh.s[e] = hs;
        ul.s[e] = f2bf(wv - bf2f(hs));
      }
      const size_t off = ((size_t)(slice * 4 + w) * 4 + kt) * 512 + lane * 8;
      *reinterpret_cast<uint4*>(WFh + off) = uh.u;
      *reinterpret_cast<uint4*>(WFl + off) = ul.u;
    }
  }
}

// ---------------------------------------------------------------------------
// Kernel 1: QKV GEMM, all-DMA ingest. Grid (6, 256): x = 64-col slice,
// y = 64-token tile. 4 waves: wave w = DMA role (sXh/sXl/sWh/sWl) and
// compute rows w*16..+16. bf16 hi/lo 3-pass (fp32-accurate).
// Outputs: Q fp16 row-major; K fp16 fragment layout; V bf16 fragment layout.
// ---------------------------------------------------------------------------
__global__ __launch_bounds__(256, 2) void qkv_gemm(
    const unsigned short* __restrict__ XFh, const unsigned short* __restrict__ XFl,
    const unsigned short* __restrict__ WFh, const unsigned short* __restrict__ WFl,
    const float* __restrict__ bq, const float* __restrict__ bk,
    const float* __restrict__ bv,
    unsigned short* __restrict__ Qh, unsigned short* __restrict__ KF,
    unsigned short* __restrict__ VF)
{
  __shared__ __align__(16) unsigned short sXh[16 * 512];  // 16 KB
  __shared__ __align__(16) unsigned short sXl[16 * 512];
  __shared__ __align__(16) unsigned short sWh[16 * 512];
  __shared__ __align__(16) unsigned short sWl[16 * 512];
  __shared__ __align__(16) unsigned short sOut[64 * 72];  // 9 KB

  const int tid  = threadIdx.x;
  const int w    = tid >> 6;
  const int lane = tid & 63;
  const int l16  = lane & 15;
  const int quad = lane >> 4;
  const int slice = blockIdx.x;                 // 0..5
  const int mat  = slice >> 1;                  // 0=Q, 1=K, 2=V
  const int fbase = (slice & 1) * 64;
  const int m0   = blockIdx.y * 64;
  const int t0   = blockIdx.y * 4;              // first 16-row tile

  // --- DMA ingest: wave w stages 16 chunks of its buffer ---
  {
    const unsigned short* src;
    unsigned short* dst;
    size_t cbase;
    if (w == 0)      { src = XFh; dst = sXh; cbase = (size_t)t0 * 4; }
    else if (w == 1) { src = XFl; dst = sXl; cbase = (size_t)t0 * 4; }
    else if (w == 2) { src = WFh; dst = sWh; cbase = (size_t)slice * 16; }
    else             { src = WFl; dst = sWl; cbase = (size_t)slice * 16; }
    const unsigned short* gp = src + cbase * 512 + lane * 8;
#pragma unroll
    for (int f = 0; f < 16; ++f)
      __builtin_amdgcn_global_load_lds(
          (g_u32*)(gp + f * 512), (l_u32*)(dst + f * 512), 16, 0, 0);
  }
  __syncthreads();

  // X A-frags for this wave's 16 rows (tile t0+w), conflict-free b128.
  bf16x8 xh[4], xl[4];
#pragma unroll
  for (int kt = 0; kt < 4; ++kt) {
    xh[kt] = *reinterpret_cast<const bf16x8*>(&sXh[(w * 4 + kt) * 512 + lane * 8]);
    xl[kt] = *reinterpret_cast<const bf16x8*>(&sXl[(w * 4 + kt) * 512 + lane * 8]);
  }

  floatx4 acc[4];
#pragma unroll
  for (int nt = 0; nt < 4; ++nt) acc[nt] = (floatx4)(0.0f);

  // C = Xh*Wh + Xl*Wh + Xh*Wl (lo*lo dropped).
#pragma unroll
  for (int nt = 0; nt < 4; ++nt) {
    bf16x8 wh[4], wl[4];
#pragma unroll
    for (int kt = 0; kt < 4; ++kt) {
      wh[kt] = *reinterpret_cast<const bf16x8*>(&sWh[(nt * 4 + kt) * 512 + lane * 8]);
      wl[kt] = *reinterpret_cast<const bf16x8*>(&sWl[(nt * 4 + kt) * 512 + lane * 8]);
    }
#pragma unroll
    for (int kt = 0; kt < 4; ++kt) {
      acc[nt] = __builtin_amdgcn_mfma_f32_16x16x32_bf16(xh[kt], wh[kt], acc[nt], 0, 0, 0);
      acc[nt] = __builtin_amdgcn_mfma_f32_16x16x32_bf16(xl[kt], wh[kt], acc[nt], 0, 0, 0);
      acc[nt] = __builtin_amdgcn_mfma_f32_16x16x32_bf16(xh[kt], wl[kt], acc[nt], 0, 0, 0);
    }
  }

  // --- Epilogue: bias + convert -> sOut [64 rows][72 pad shorts] ---
  const float* bias_p = (mat == 0) ? bq : (mat == 1) ? bk : bv;
  float bias[4];
#pragma unroll
  for (int nt = 0; nt < 4; ++nt) bias[nt] = bias_p[fbase + nt * 16 + l16];

#pragma unroll
  for (int nt = 0; nt < 4; ++nt)
#pragma unroll
    for (int r = 0; r < 4; ++r) {
      const float val = acc[nt][r] + bias[nt];
      sOut[(w * 16 + quad * 4 + r) * 72 + nt * 16 + l16] =
          (mat == 2) ? f2bf(val) : f2h(val);
    }
  __syncthreads();

  // --- Store phase: 512 x 16-B dest-contiguous chunks, 2/thread ---
  if (mat == 0) {
#pragma unroll
    for (int i = 0; i < 2; ++i) {
      const int c = i * 256 + tid, row = c >> 3, c8 = c & 7;
      *reinterpret_cast<uint4*>(Qh + (size_t)(m0 + row) * DIM + fbase + c8 * 8) =
          *reinterpret_cast<const uint4*>(&sOut[row * 72 + c8 * 8]);
    }
  } else if (mat == 1) {
#pragma unroll
    for (int i = 0; i < 2; ++i) {
      const int c = i * 256 + tid, row = c >> 3, c8 = c & 7;
      const int token = m0 + row;
      const int bK = token >> 12, j = (token & (NSEQ - 1)) >> 6, nl = token & 63;
      const int nt = nl >> 4, lk = nl & 15;
      const int feat = fbase + c8 * 8;
      const int kt = feat >> 5, qd = (feat >> 3) & 3;
      const size_t addr =
          ((((size_t)(bK * 64 + j) * 4 + nt) * 4 + kt) * 64 + qd * 16 + lk) * 8;
      *reinterpret_cast<uint4*>(KF + addr) =
          *reinterpret_cast<const uint4*>(&sOut[row * 72 + c8 * 8]);
    }
  } else {
#pragma unroll
    for (int i = 0; i < 2; ++i) {
      const int c = i * 256 + tid;
      const int d_loc = c & 63, key8 = c >> 6;            // key8: 0..7
      const int d = fbase + d_loc, nt = d >> 4, lv = d & 15;
      const int kt = key8 >> 2, qd = key8 & 3;
      const int token0 = m0 + key8 * 8;
      const int bV = token0 >> 12, j = (token0 & (NSEQ - 1)) >> 6;
      unsigned short tmp[8];
#pragma unroll
      for (int e = 0; e < 8; ++e) tmp[e] = sOut[(key8 * 8 + e) * 72 + d_loc];
      const size_t addr =
          ((((size_t)(bV * 64 + j) * 8 + nt) * 2 + kt) * 64 + qd * 16 + lv) * 8;
      *reinterpret_cast<uint4*>(VF + addr) = *reinterpret_cast<const uint4*>(tmp);
    }
  }
}

// ---------------------------------------------------------------------------
// Kernel 2: flash attention quarter (R10 body), XCD-affine swizzle:
// blockIdx.x = qt*16 + (b*4 + sp). With round-robin %8 XCD dispatch, XCD x
// serves (b*4+sp) in {x, x+8}: per-XCD K/V slice = 2x2MB = 4MB, L2-resident.
// 1024 blocks x 128 threads (2 waves, M=32/wave).
// ---------------------------------------------------------------------------
__global__ __launch_bounds__(128, 2) void attn(
    const unsigned short* __restrict__ Qh, const unsigned short* __restrict__ KF,
    const unsigned short* __restrict__ VF,
    unsigned short* __restrict__ Opart, float* __restrict__ Lpart)
{
  __shared__ __align__(16) unsigned short sK[16 * 512];    // 16 K frags, 16 KB
  __shared__ __align__(16) unsigned short sV[16 * 512];    // 16 V frags, 16 KB
  __shared__ __align__(16) unsigned short sP[2 * 32 * 64]; // swizzled, 8 KB

  const int tid  = threadIdx.x;
  const int w    = tid >> 6;
  const int lane = tid & 63;
  const int l16  = lane & 15;
  const int quad = lane >> 4;
  // XCD-affine decode: low 4 bits = (b*4+sp) -> pinned to XCD via %8.
  const int bsp  = blockIdx.x & 15;
  const int qt   = blockIdx.x >> 4;
  const int b    = bsp >> 2;
  const int sp   = bsp & 3;
  const int q0   = qt * 64;
  const int j0   = sp * JSPL, j1 = j0 + JSPL;

  unsigned short* sPw = &sP[w * 32 * 64];

  int wkey[2][4];
#pragma unroll
  for (int mt = 0; mt < 2; ++mt)
#pragma unroll
    for (int r = 0; r < 4; ++r) {
      const int m = mt * 16 + quad * 4 + r;
      wkey[mt][r] = (m ^ (m >> 3)) & 7;
    }
  int rkey[2];
#pragma unroll
  for (int mt = 0; mt < 2; ++mt) {
    const int m = mt * 16 + l16;
    rkey[mt] = (m ^ (m >> 3)) & 7;
  }

  f16x8 aq[2][4];
#pragma unroll
  for (int mt = 0; mt < 2; ++mt) {
    const unsigned short* qp =
        Qh + (size_t)(b * NSEQ + q0 + w * 32 + mt * 16 + l16) * DIM + quad * 8;
#pragma unroll
    for (int kt = 0; kt < 4; ++kt)
      aq[mt][kt] = *reinterpret_cast<const f16x8*>(qp + kt * 32);
  }

  floatx4 o[2][8];
#pragma unroll
  for (int mt = 0; mt < 2; ++mt)
#pragma unroll
    for (int nt = 0; nt < 8; ++nt) o[mt][nt] = (floatx4)(0.0f);
  float l_part[2][4] = {{0, 0, 0, 0}, {0, 0, 0, 0}};

  for (int j = j0; j < j1; ++j) {
    {
      const unsigned short* src = (w == 0) ? KF : VF;
      unsigned short* dst = (w == 0) ? sK : sV;
      const unsigned short* gp = src + (size_t)(b * 64 + j) * 8192 + lane * 8;
#pragma unroll
      for (int f = 0; f < 16; ++f)
        __builtin_amdgcn_global_load_lds(
            (g_u32*)(gp + f * 512), (l_u32*)(dst + f * 512), 16, 0, 0);
    }
    __syncthreads();

    f16x8 bk[4][4];
#pragma unroll
    for (int nt = 0; nt < 4; ++nt)
#pragma unroll
      for (int kt = 0; kt < 4; ++kt)
        bk[nt][kt] = *reinterpret_cast<const f16x8*>(
            &sK[(nt * 4 + kt) * 512 + lane * 8]);

    floatx4 s[2][4];
#pragma unroll
    for (int mt = 0; mt < 2; ++mt)
#pragma unroll
      for (int nt = 0; nt < 4; ++nt) s[mt][nt] = (floatx4)(0.0f);
#pragma unroll
    for (int nt = 0; nt < 4; ++nt)
#pragma unroll
      for (int kt = 0; kt < 4; ++kt)
#pragma unroll
        for (int mt = 0; mt < 2; ++mt)
          s[mt][nt] = __builtin_amdgcn_mfma_f32_16x16x32_f16(aq[mt][kt], bk[nt][kt], s[mt][nt], 0, 0, 0);

#pragma unroll
    for (int mt = 0; mt < 2; ++mt)
#pragma unroll
      for (int nt = 0; nt < 4; ++nt)
#pragma unroll
        for (int r = 0; r < 4; ++r) {
          const float p = __expf(s[mt][nt][r]);
          l_part[mt][r] += p;
          sPw[(mt * 16 + quad * 4 + r) * 64 +
              (((nt * 2 + (l16 >> 3)) ^ wkey[mt][r]) << 3) + (l16 & 7)] = f2bf(p);
        }

    bf16x8 ap[2][2];
#pragma unroll
    for (int mt = 0; mt < 2; ++mt)
#pragma unroll
      for (int kt = 0; kt < 2; ++kt)
        ap[mt][kt] = *reinterpret_cast<const bf16x8*>(
            &sPw[(mt * 16 + l16) * 64 + (((kt * 4 + quad) ^ rkey[mt]) << 3)]);

#pragma unroll
    for (int nt = 0; nt < 8; ++nt) {
      bf16x8 bv[2];
#pragma unroll
      for (int kt = 0; kt < 2; ++kt)
        bv[kt] = *reinterpret_cast<const bf16x8*>(
            &sV[(nt * 2 + kt) * 512 + lane * 8]);
#pragma unroll
      for (int kt = 0; kt < 2; ++kt)
#pragma unroll
        for (int mt = 0; mt < 2; ++mt)
          o[mt][nt] = __builtin_amdgcn_mfma_f32_16x16x32_bf16(ap[mt][kt], bv[kt], o[mt][nt], 0, 0, 0);
    }
    __syncthreads();
  }

#pragma unroll
  for (int mt = 0; mt < 2; ++mt)
#pragma unroll
    for (int r = 0; r < 4; ++r) {
      float l = l_part[mt][r];
      l += __shfl_xor(l, 1);
      l += __shfl_xor(l, 2);
      l += __shfl_xor(l, 4);
      l += __shfl_xor(l, 8);
      const float inv = 1.0f / l;
      const int t = q0 + w * 32 + mt * 16 + quad * 4 + r;
      const size_t ob = ((size_t)sp * TOKENS + b * NSEQ + t) * DIM;
#pragma unroll
      for (int nt = 0; nt < 8; ++nt)
        Opart[ob + nt * 16 + l16] = f2bf(o[mt][nt][r] * inv);
      if (l16 == 0) Lpart[sp * TOKENS + b * NSEQ + t] = l;
    }
}

// ---------------------------------------------------------------------------
// Kernel 3: combine quarters + residual. out = sum(l_s O_s)/sum(l_s) + x.
// ---------------------------------------------------------------------------
__global__ __launch_bounds__(256) void combine(
    const unsigned short* __restrict__ Opart, const float* __restrict__ Lpart,
    const float* __restrict__ X, float* __restrict__ Out)
{
  const int idx = blockIdx.x * 256 + threadIdx.x;
  const int T   = idx >> 4;
  const int c8  = (idx & 15) * 8;
  float ls[SPLITS], tot = 0.0f;
#pragma unroll
  for (int s = 0; s < SPLITS; ++s) { ls[s] = Lpart[s * TOKENS + T]; tot += ls[s]; }
  const float winv = 1.0f / tot;

  const size_t pa = (size_t)T * DIM + c8;
  const float4 x0 = *reinterpret_cast<const float4*>(X + pa);
  const float4 x1 = *reinterpret_cast<const float4*>(X + pa + 4);
  float os[8] = {x0.x, x0.y, x0.z, x0.w, x1.x, x1.y, x1.z, x1.w};
#pragma unroll
  for (int s = 0; s < SPLITS; ++s) {
    const float ws = ls[s] * winv;
    const uint4 u = *reinterpret_cast<const uint4*>(
        Opart + (size_t)s * TOKENS * DIM + pa);
    const unsigned uu[4] = {u.x, u.y, u.z, u.w};
#pragma unroll
    for (int e = 0; e < 4; ++e) {
      os[2 * e]     += ws * bf2f(uu[e] & 0xffff);
      os[2 * e + 1] += ws * bf2f(uu[e] >> 16);
    }
  }
  float4 o0 = {os[0], os[1], os[2], os[3]};
  float4 o1 = {os[4], os[5], os[6], os[7]};
  *reinterpret_cast<float4*>(Out + pa)     = o0;
  *reinterpret_cast<float4*>(Out + pa + 4) = o1;
}

// ---------------------------------------------------------------------------
extern "C" void kernel_launch(void* const* d_in, const int* in_sizes, int n_in,
                              void* d_out, int out_size, void* d_ws, size_t ws_size,
                              hipStream_t stream) {
  const float* X  = (const float*)d_in[0];
  const float* Wq = (const float*)d_in[1];
  const float* bq = (const float*)d_in[2];
  const float* Wk = (const float*)d_in[3];
  const float* bk = (const float*)d_in[4];
  const float* Wv = (const float*)d_in[5];
  const float* bv = (const float*)d_in[6];
  float* Out = (float*)d_out;

  const size_t MAT = (size_t)TOKENS * DIM;   // 2 M elements
  unsigned short* Qh    = (unsigned short*)d_ws;          // fp16 row-major, 4MB
  unsigned short* KF    = Qh + MAT;                       // fp16 frag, 4MB
  unsigned short* VF    = KF + MAT;                       // bf16 frag, 4MB
  unsigned short* XFh   = VF + MAT;                       // bf16 frag, 4MB
  unsigned short* XFl   = XFh + MAT;                      // bf16 frag, 4MB
  unsigned short* WFh   = XFl + MAT;                      // 96 KB
  unsigned short* WFl   = WFh + 6 * 16 * 512;             // 96 KB
  unsigned short* Opart = WFl + 6 * 16 * 512;             // bf16, SPLITS x 4MB
  float*          Lpart = (float*)(Opart + (size_t)SPLITS * MAT);
  // total ws ~ 36.5 MB

  prep<<<262, 256, 0, stream>>>(X, Wq, Wk, Wv, XFh, XFl, WFh, WFl);
  qkv_gemm<<<dim3(6, 256), 256, 0, stream>>>(XFh, XFl, WFh, WFl, bq, bk, bv,
                                             Qh, KF, VF);
  attn<<<4 * SPLITS * 64, 128, 0, stream>>>(Qh, KF, VF, Opart, Lpart);
  combine<<<(TOKENS * DIM) / (256 * 8), 256, 0, stream>>>(Opart, Lpart, X, Out);
}